// Round 2
// baseline (139.914 us; speedup 1.0000x reference)
//
#include <hip/hip_runtime.h>

// LengthRegulator: b=16, t_x=1024, d=256, out_len=7168 (fixed by setup_inputs)
#define B       16
#define TX      1024
#define D       256
#define OUT_LEN 7168
#define F4_PER_ROW (D / 4)          // 64 float4 per output row
#define TOTAL_F4 (B * OUT_LEN * F4_PER_ROW)   // 7,340,032

// ---------------------------------------------------------------------------
// Kernel 1: per-batch inclusive scan of repeat_count, then scatter the
// per-output-row source index table src[b*OUT_LEN + j] = b*TX + i for
// j in [cum[i-1], cum[i]), -1 for the zero tail. Also writes lengths (as
// float) into the tail of d_out. One block per batch, 256 threads.
// ---------------------------------------------------------------------------
__global__ __launch_bounds__(256) void lr_scan_src_kernel(
        const int* __restrict__ rc,      // (B, TX) int32
        int* __restrict__ src,           // (B, OUT_LEN) int32 out (workspace)
        float* __restrict__ len_out)     // d_out + B*OUT_LEN*D, B floats
{
    __shared__ int part[256];
    const int b = blockIdx.x;
    const int t = threadIdx.x;

    const int4* rc4 = (const int4*)(rc + b * TX);
    int4 v = rc4[t];
    const int s0 = v.x;
    const int s1 = s0 + v.y;
    const int s2 = s1 + v.z;
    const int s3 = s2 + v.w;

    part[t] = s3;
    __syncthreads();

    // Hillis-Steele inclusive scan over the 256 per-thread sums
    #pragma unroll
    for (int off = 1; off < 256; off <<= 1) {
        int tmp = (t >= off) ? part[t - off] : 0;
        __syncthreads();
        part[t] += tmp;
        __syncthreads();
    }

    const int excl = part[t] - s3;   // exclusive prefix of this thread's group
    const int total = part[255];     // valid: last write was barrier-protected

    // scatter source indices for this thread's 4 phonemes
    int* srow = src + b * OUT_LEN;
    const int gbase = b * TX + 4 * t;
    int st[5];
    st[0] = excl;
    st[1] = excl + s0;
    st[2] = excl + s1;
    st[3] = excl + s2;
    st[4] = excl + s3;
    #pragma unroll
    for (int k = 0; k < 4; k++) {
        const int g = gbase + k;
        for (int j = st[k]; j < st[k + 1]; j++) srow[j] = g;
    }

    // zero tail: rows [total, OUT_LEN) have no source
    for (int j = total + t; j < OUT_LEN; j += 256) srow[j] = -1;

    if (t == 255) {
        len_out[b] = (float)total;   // lengths[b] = cum[b, TX-1]
    }
}

// ---------------------------------------------------------------------------
// Kernel 2: streaming expand. out4[e] = x4[src[row]*64 + lane] or 0.
// 4 independent float4 elements per thread (ILP), fully coalesced: lanes of
// a wave cover one output row (64 x float4 = 1 KB); src[row] is wave-uniform.
// ---------------------------------------------------------------------------
__global__ __launch_bounds__(256) void lr_expand_kernel(
        const float4* __restrict__ x4,   // (B*TX, 64) float4
        const int* __restrict__ src,     // (B*OUT_LEN)
        float4* __restrict__ out4)       // (B*OUT_LEN, 64) float4
{
    const int e0 = blockIdx.x * 256 + threadIdx.x;
    const int stride = TOTAL_F4 / 4;     // 1,835,008 (grid covers exactly 4x)

    #pragma unroll
    for (int k = 0; k < 4; k++) {
        const int e = e0 + k * stride;
        const int s = src[e >> 6];       // wave-uniform (lanes share the row)
        float4 val = make_float4(0.f, 0.f, 0.f, 0.f);
        if (s >= 0) {
            val = x4[((size_t)s << 6) | (e & 63)];
        }
        out4[e] = val;
    }
}

extern "C" void kernel_launch(void* const* d_in, const int* in_sizes, int n_in,
                              void* d_out, int out_size, void* d_ws, size_t ws_size,
                              hipStream_t stream) {
    const float* x  = (const float*)d_in[0];
    const int*   rc = (const int*)d_in[1];     // repeat_count (int32 on device)
    float* out = (float*)d_out;
    float* len_out = out + (size_t)B * OUT_LEN * D;   // lengths chunk (B floats)
    int* src = (int*)d_ws;                            // (B, OUT_LEN) int32 scratch

    lr_scan_src_kernel<<<B, 256, 0, stream>>>(rc, src, len_out);

    const int grid = TOTAL_F4 / (256 * 4);            // 7168 blocks
    lr_expand_kernel<<<grid, 256, 0, stream>>>(
        (const float4*)x, src, (float4*)out);
}